// Round 13
// baseline (452.419 us; speedup 1.0000x reference)
//
#include <hip/hip_runtime.h>
#include <stdint.h>

#define CONF 0.96f
#define IOUT 0.45f
#define NA 25200
#define DIM 85
#define NC 80
#define NIMG 8
#define NCAND 2048
#define CAPRAW 4096
#define NDET 300
#define CH 64                         // mask tile edge
#define NCH (NCAND / CH)              // 32
#define APB 112
#define NSEG (NA / APB)               // 225 segments per image
#define SEGCAP 96                     // cap per segment (E=7.3, P(>96)~1e-60)

// ---------------- K1: light filter (obj-probe, no streaming) -----------
__global__ __launch_bounds__(128) void k1_filter(
    const float* __restrict__ pred, int* __restrict__ bcnt,
    uint64_t* __restrict__ raw_k) {
    __shared__ int   hot[APB];
    __shared__ float hobj[APB];
    __shared__ uint64_t l_k[SEGCAP];
    __shared__ int   l_hot, l_cnt;
    int tid = threadIdx.x;
    int img = blockIdx.y;
    int blk = blockIdx.x;
    int a0 = blk * APB;
    if (tid == 0) { l_hot = 0; l_cnt = 0; }
    __syncthreads();

    if (tid < APB) {                  // obj probe: 1 load / anchor
        float obj = pred[((size_t)img * NA + a0 + tid) * DIM + 4];
        if (obj > CONF) {
            int p = atomicAdd(&l_hot, 1);
            hot[p] = tid; hobj[p] = obj;
        }
    }
    __syncthreads();
    int items = l_hot * NC;           // typically ~360 -> 3 iters
    for (int w = tid; w < items; w += 128) {
        int hi = w / NC;
        int c = w - hi * NC;
        int al = hot[hi];
        float s = pred[((size_t)img * NA + a0 + al) * DIM + 5 + c] * hobj[hi];
        if (s > CONF) {
            int q = atomicAdd(&l_cnt, 1);
            if (q < SEGCAP)
                l_k[q] = ((uint64_t)__float_as_uint(s) << 32)
                       | (uint32_t)(~(uint32_t)((a0 + al) * NC + c));
        }
    }
    __syncthreads();
    int c = l_cnt; if (c > SEGCAP) c = SEGCAP;
    if (tid == 0) bcnt[img * 256 + blk] = c;
    uint64_t* seg = raw_k + ((size_t)img * NSEG + blk) * SEGCAP;
    for (int i = tid; i < c; i += 128) seg[i] = l_k[i];
}

// ---------------- K2: prefix-scan compaction + rank sort ---------------
__global__ __launch_bounds__(256) void k2_rank(
    const float* __restrict__ pred,
    const int* __restrict__ bcnt, const uint64_t* __restrict__ raw_k,
    int* __restrict__ n_arr,
    float* __restrict__ score, int* __restrict__ label,
    float* __restrict__ ox1, float* __restrict__ oy1,
    float* __restrict__ ox2, float* __restrict__ oy2,
    float* __restrict__ area,
    float* __restrict__ rx1, float* __restrict__ ry1,
    float* __restrict__ rx2, float* __restrict__ ry2) {
    __shared__ uint64_t keys[CAPRAW];               // 32 KB
    __shared__ int sc[256];
    int img = blockIdx.y;
    int unit = blockIdx.x;
    int tid = threadIdx.x;
    int c = (tid < NSEG) ? bcnt[img * 256 + tid] : 0;
    sc[tid] = c;
    __syncthreads();
    for (int d = 1; d < 256; d <<= 1) {             // Hillis-Steele
        int v = (tid >= d) ? sc[tid - d] : 0;
        __syncthreads();
        sc[tid] += v;
        __syncthreads();
    }
    int total = sc[255];
    int m = total < CAPRAW ? total : CAPRAW;
    if (unit == 0 && tid == 0) n_arr[img] = m < NCAND ? m : NCAND;
    int off = sc[tid] - c;                          // exclusive prefix
    const uint64_t* seg = raw_k + ((size_t)img * NSEG + tid) * SEGCAP;
    for (int k = 0; k < c; ++k) {                   // segmented gather
        int pos = off + k;
        if (pos < CAPRAW) keys[pos] = seg[k];
    }
    for (int j = tid; j < CAPRAW; j += 256)
        if (j >= m) keys[j] = 0;                    // pad keys never rank
    __syncthreads();
    if (unit * 256 >= m) return;                    // block-uniform exit

    int idx = unit * 256 + tid;
    bool valid = idx < m;
    uint64_t my = keys[idx];                        // 0 for invalid
    int mt = (m + 7) & ~7;
    int rank = 0;
#pragma unroll 8
    for (int j = 0; j < mt; ++j) rank += (keys[j] > my) ? 1 : 0;

    if (valid && rank < NCAND) {
        float s = __uint_as_float((uint32_t)(my >> 32));
        uint32_t myf = ~((uint32_t)my);
        int anchor = (int)(myf / NC);
        int lab = (int)(myf - (uint32_t)anchor * NC);
        const float* p = pred + ((size_t)img * NA + anchor) * DIM;
        float cx = p[0], cy = p[1], wv = p[2], hv = p[3];
        float x1 = cx - 0.5f * wv, y1 = cy - 0.5f * hv;
        float x2 = cx + 0.5f * wv, y2 = cy + 0.5f * hv;
        float offl = (float)lab * 4.0f;
        size_t o = (size_t)img * NCAND + rank;
        score[o] = s; label[o] = lab;
        rx1[o] = x1; ry1[o] = y1; rx2[o] = x2; ry2[o] = y2;
        float o1 = x1 + offl, o2 = y1 + offl, o3 = x2 + offl, o4 = y2 + offl;
        ox1[o] = o1; oy1[o] = o2; ox2[o] = o3; oy2[o] = o4;
        area[o] = (o3 - o1) * (o4 - o2);            // same op order as ref
    }
}

// ---------------- K3: 64x64 tiles, write-all (no memset) ---------------
__global__ __launch_bounds__(64) void k3_mask(
    const int* __restrict__ n_arr,
    const float* __restrict__ ox1, const float* __restrict__ oy1,
    const float* __restrict__ ox2, const float* __restrict__ oy2,
    const float* __restrict__ area, uint64_t* __restrict__ mask64) {
    __shared__ float jx1[CH], jy1[CH], jx2[CH], jy2[CH], jar[CH];
    int img = blockIdx.y;
    int n = n_arr[img];
    int ci = blockIdx.x >> 5, cj = blockIdx.x & 31;
    int t = threadIdx.x;
    size_t base = (size_t)img * NCAND;
    int i = ci * CH + t;
    uint64_t w = 0;
    if (cj >= ci && ci * CH < n && cj * CH < n) {   // block-uniform
        {
            int j = cj * CH + t;
            float x1 = 0.f, y1 = 0.f, x2 = 0.f, y2 = 0.f, ar = 0.f;
            if (j < n) {
                x1 = ox1[base + j]; y1 = oy1[base + j];
                x2 = ox2[base + j]; y2 = oy2[base + j]; ar = area[base + j];
            }
            jx1[t] = x1; jy1[t] = y1; jx2[t] = x2; jy2[t] = y2; jar[t] = ar;
        }
        __syncthreads();
        float ax1 = 0.f, ay1 = 0.f, ax2 = 0.f, ay2 = 0.f, aar = 0.f;
        if (i < n) {
            ax1 = ox1[base + i]; ay1 = oy1[base + i];
            ax2 = ox2[base + i]; ay2 = oy2[base + i]; aar = area[base + i];
        }
        int jg0 = cj * CH;
#pragma unroll 8
        for (int jj = 0; jj < CH; ++jj) {
            float ltx = fmaxf(ax1, jx1[jj]), lty = fmaxf(ay1, jy1[jj]);
            float rbx = fminf(ax2, jx2[jj]), rby = fminf(ay2, jy2[jj]);
            float ww = fmaxf(rbx - ltx, 0.f), hh = fmaxf(rby - lty, 0.f);
            float inter = ww * hh;
            float iou = inter / (aar + jar[jj] - inter + 1e-9f);  // IEEE div
            w |= (iou > IOUT && (jg0 + jj) > i) ? (1ull << jj) : 0ull;
        }
    }
    mask64[(base + (size_t)i) * NCH + cj] = w;
}

// ---------------- K4: serial greedy scan + top-300 output --------------
__global__ void k4_scan(const int* __restrict__ n_arr,
                        const uint32_t* __restrict__ mask,
                        const float* __restrict__ score, const int* __restrict__ label,
                        const float* __restrict__ rx1, const float* __restrict__ ry1,
                        const float* __restrict__ rx2, const float* __restrict__ ry2,
                        float* __restrict__ out) {
    int img = blockIdx.x;
    int lane = threadIdx.x;   // 64 threads = 1 wave
    int n = n_arr[img];
    size_t cbase = (size_t)img * NCAND;
    const uint32_t* rowp = mask + cbase * 64 + lane;
    float* outp = out + (size_t)img * NDET * 6;

    uint32_t removed = 0;
    int kcnt = 0;
    constexpr int PF = 32;
    uint32_t buf[PF];
#pragma unroll
    for (int k = 0; k < PF; ++k) buf[k] = rowp[(size_t)k * 64];
    for (int ib = 0; ib < n; ib += PF) {
#pragma unroll
        for (int k = 0; k < PF; ++k) {
            int i = ib + k;
            uint32_t row = buf[k];
            int pi = i + PF; if (pi > NCAND - 1) pi = NCAND - 1;
            buf[k] = rowp[(size_t)pi * 64];
            // blocked layout: word at lane i>>5, bit i&31. i uniform.
            uint32_t w = (uint32_t)__builtin_amdgcn_readlane((int)removed, i >> 5);
            uint32_t kept = ((w >> (i & 31)) & 1u) ^ 1u;
            kcnt += (int)kept;                      // phantom i>=n harmless
            removed |= row & (0u - kept);
        }
        if (kcnt >= NDET) break;                    // uniform early stop
    }

    int j0 = lane << 5;
    uint32_t vmask = (j0 + 32 <= n) ? 0xffffffffu
                   : (j0 >= n ? 0u : ((1u << (n - j0)) - 1u));
    uint32_t keptw = ~removed & vmask;
    int cntk = __popc(keptw);
    int pre = cntk;
    for (int d = 1; d < 64; d <<= 1) {              // inclusive prefix
        int tv = __shfl_up(pre, d);
        if (lane >= d) pre += tv;
    }
    int totalk = __shfl(pre, 63);
    int r = pre - cntk;                             // exclusive prefix
    uint32_t wvb = keptw;
    while (wvb) {
        int b = __builtin_ctz(wvb);
        wvb &= wvb - 1;
        if (r >= NDET) break;
        int j = j0 + b;
        float* o = outp + (size_t)r * 6;
        o[0] = rx1[cbase + j]; o[1] = ry1[cbase + j];
        o[2] = rx2[cbase + j]; o[3] = ry2[cbase + j];
        o[4] = score[cbase + j]; o[5] = (float)label[cbase + j];
        ++r;
    }
    int nk = totalk < NDET ? totalk : NDET;
    for (int idx = nk * 6 + lane; idx < NDET * 6; idx += 64) outp[idx] = 0.0f;
}

// ---------------- launch: DISCRIMINATION ROUND -------------------------
// Each kernel x4 in bursts (all idempotent; output identical).
// T = 179.2 + 3*Sum(k) + 12*g  combined with R12's  Sum(k) + 5g = 97.9
// solves (Sum, g) exactly; any ~40us kernel surfaces by NAME in top-5.
extern "C" void kernel_launch(void* const* d_in, const int* in_sizes, int n_in,
                              void* d_out, int out_size, void* d_ws, size_t ws_size,
                              hipStream_t stream) {
    const float* pred = (const float*)d_in[0];
    float* out = (float*)d_out;
    char* w = (char*)d_ws;

    const size_t A_BC  = 0;                                 // 8*256 ints
    const size_t A_RK  = 8192;                              // 8*225*96*8 keys
    const size_t SA    = A_RK + (size_t)NIMG * NSEG * SEGCAP * 8;
    const size_t A_N   = SA;                                // 8 ints (pad 256)
    const size_t SB    = SA + 256;
    const size_t SZ_S  = (size_t)NIMG * NCAND * 4;          // 64 KiB each

    int*      bcnt  = (int*)(w + A_BC);
    uint64_t* raw_k = (uint64_t*)(w + A_RK);
    int*      n_arr = (int*)(w + A_N);
    float* score = (float*)(w + SB + 0 * SZ_S);
    int*   label = (int*)(w + SB + 1 * SZ_S);
    float* ox1   = (float*)(w + SB + 2 * SZ_S);
    float* oy1   = (float*)(w + SB + 3 * SZ_S);
    float* ox2   = (float*)(w + SB + 4 * SZ_S);
    float* oy2   = (float*)(w + SB + 5 * SZ_S);
    float* area  = (float*)(w + SB + 6 * SZ_S);
    float* rx1   = (float*)(w + SB + 7 * SZ_S);
    float* ry1   = (float*)(w + SB + 8 * SZ_S);
    float* rx2   = (float*)(w + SB + 9 * SZ_S);
    float* ry2   = (float*)(w + SB + 10 * SZ_S);
    uint64_t* mask64 = (uint64_t*)(w + SB + 11 * SZ_S);     // 4 MiB
    uint32_t* mask32 = (uint32_t*)mask64;

    dim3 g1(NSEG, NIMG);                                    // 225 x 8
    dim3 g2(CAPRAW / 256, NIMG);                            // 16 x 8
    dim3 g3(NCH * NCH, NIMG);                               // 1024 x 8
    for (int r = 0; r < 4; ++r)
        k1_filter<<<g1, 128, 0, stream>>>(pred, bcnt, raw_k);
    for (int r = 0; r < 4; ++r)
        k2_rank<<<g2, 256, 0, stream>>>(pred, bcnt, raw_k, n_arr,
            score, label, ox1, oy1, ox2, oy2, area, rx1, ry1, rx2, ry2);
    for (int r = 0; r < 4; ++r)
        k3_mask<<<g3, CH, 0, stream>>>(n_arr, ox1, oy1, ox2, oy2, area, mask64);
    for (int r = 0; r < 4; ++r)
        k4_scan<<<NIMG, 64, 0, stream>>>(n_arr, mask32, score, label,
            rx1, ry1, rx2, ry2, out);
}

// Round 14
// 164.083 us; speedup vs baseline: 2.7573x; 2.7573x over previous
//
#include <hip/hip_runtime.h>
#include <stdint.h>

#define CONF 0.96f
#define IOUT 0.45f
#define NA 25200
#define DIM 85
#define NC 80
#define NIMG 8
#define NCAND 2048
#define CAPRAW 4096
#define NDET 300
#define CH 64                         // mask tile edge
#define NCH (NCAND / CH)              // 32
#define APB 112
#define NSEG (NA / APB)               // 225 segments per image
#define SEGCAP 96                     // cap per segment (E=7.3, P(>96)~1e-60)
#define K2U 64                        // candidates per k2 block
#define K2P 4                         // j-range split parts per candidate

// ---------------- K1: light filter (obj-probe, no streaming) -----------
__global__ __launch_bounds__(128) void k1_filter(
    const float* __restrict__ pred, int* __restrict__ bcnt,
    uint64_t* __restrict__ raw_k) {
    __shared__ int   hot[APB];
    __shared__ float hobj[APB];
    __shared__ uint64_t l_k[SEGCAP];
    __shared__ int   l_hot, l_cnt;
    int tid = threadIdx.x;
    int img = blockIdx.y;
    int blk = blockIdx.x;
    int a0 = blk * APB;
    if (tid == 0) { l_hot = 0; l_cnt = 0; }
    __syncthreads();

    if (tid < APB) {                  // obj probe: 1 load / anchor
        float obj = pred[((size_t)img * NA + a0 + tid) * DIM + 4];
        if (obj > CONF) {
            int p = atomicAdd(&l_hot, 1);
            hot[p] = tid; hobj[p] = obj;
        }
    }
    __syncthreads();
    int items = l_hot * NC;           // typically ~360 -> 3 iters
    for (int w = tid; w < items; w += 128) {
        int hi = w / NC;
        int c = w - hi * NC;
        int al = hot[hi];
        float s = pred[((size_t)img * NA + a0 + al) * DIM + 5 + c] * hobj[hi];
        if (s > CONF) {
            int q = atomicAdd(&l_cnt, 1);
            if (q < SEGCAP)
                l_k[q] = ((uint64_t)__float_as_uint(s) << 32)
                       | (uint32_t)(~(uint32_t)((a0 + al) * NC + c));
        }
    }
    __syncthreads();
    int c = l_cnt; if (c > SEGCAP) c = SEGCAP;
    if (tid == 0) bcnt[img * 256 + blk] = c;
    uint64_t* seg = raw_k + ((size_t)img * NSEG + blk) * SEGCAP;
    for (int i = tid; i < c; i += 128) seg[i] = l_k[i];
}

// ---------------- K2: rank sort, x4 range-split ------------------------
// R13 analysis: old shape ran the 1650-iter serial loop on only 56 of 256
// CUs. Now: 64 candidates/block x 4 j-range parts (256 thr), grid (64,8)
// -> ~208 active blocks, serial length /4. Work & tie semantics identical.
__global__ __launch_bounds__(256) void k2_rank(
    const float* __restrict__ pred,
    const int* __restrict__ bcnt, const uint64_t* __restrict__ raw_k,
    int* __restrict__ n_arr,
    float* __restrict__ score, int* __restrict__ label,
    float* __restrict__ ox1, float* __restrict__ oy1,
    float* __restrict__ ox2, float* __restrict__ oy2,
    float* __restrict__ area,
    float* __restrict__ rx1, float* __restrict__ ry1,
    float* __restrict__ rx2, float* __restrict__ ry2) {
    __shared__ uint64_t keys[CAPRAW];               // 32 KB
    __shared__ int sc[256];
    __shared__ int rk[K2U][K2P];
    int img = blockIdx.y;
    int unit = blockIdx.x;
    int tid = threadIdx.x;
    int c = (tid < NSEG) ? bcnt[img * 256 + tid] : 0;
    sc[tid] = c;
    __syncthreads();
    for (int d = 1; d < 256; d <<= 1) {             // Hillis-Steele
        int v = (tid >= d) ? sc[tid - d] : 0;
        __syncthreads();
        sc[tid] += v;
        __syncthreads();
    }
    int total = sc[255];
    int m = total < CAPRAW ? total : CAPRAW;
    if (unit == 0 && tid == 0) n_arr[img] = m < NCAND ? m : NCAND;
    if (unit * K2U >= m) return;                    // block-uniform exit

    int off = sc[tid] - c;                          // exclusive prefix
    const uint64_t* seg = raw_k + ((size_t)img * NSEG + tid) * SEGCAP;
    for (int k = 0; k < c; ++k) {                   // segmented gather
        int pos = off + k;
        if (pos < CAPRAW) keys[pos] = seg[k];
    }
    for (int j = tid; j < CAPRAW; j += 256)
        if (j >= m) keys[j] = 0;                    // pad keys never rank
    __syncthreads();

    int cand = tid & (K2U - 1);
    int part = tid >> 6;                            // 0..3
    int idx = unit * K2U + cand;
    bool valid = idx < m;
    uint64_t my = keys[idx];                        // 0 for invalid
    int mt = (m + 7) & ~7;                          // mult of 8
    int q = ((mt + 31) >> 5) << 3;                  // ceil(mt/4), mult of 8
    int lo = part * q;
    int hi = lo + q; if (hi > mt) hi = mt;          // both mult of 8
    int r = 0;
#pragma unroll 8
    for (int j = lo; j < hi; ++j) r += (keys[j] > my) ? 1 : 0;
    rk[cand][part] = r;
    __syncthreads();
    if (part == 0) {
        int rank = rk[cand][0] + rk[cand][1] + rk[cand][2] + rk[cand][3];
        if (valid && rank < NCAND) {
            float s = __uint_as_float((uint32_t)(my >> 32));
            uint32_t myf = ~((uint32_t)my);
            int anchor = (int)(myf / NC);
            int lab = (int)(myf - (uint32_t)anchor * NC);
            const float* p = pred + ((size_t)img * NA + anchor) * DIM;
            float cx = p[0], cy = p[1], wv = p[2], hv = p[3];
            float x1 = cx - 0.5f * wv, y1 = cy - 0.5f * hv;
            float x2 = cx + 0.5f * wv, y2 = cy + 0.5f * hv;
            float offl = (float)lab * 4.0f;
            size_t o = (size_t)img * NCAND + rank;
            score[o] = s; label[o] = lab;
            rx1[o] = x1; ry1[o] = y1; rx2[o] = x2; ry2[o] = y2;
            float o1 = x1 + offl, o2 = y1 + offl, o3 = x2 + offl, o4 = y2 + offl;
            ox1[o] = o1; oy1[o] = o2; ox2[o] = o3; oy2[o] = o4;
            area[o] = (o3 - o1) * (o4 - o2);        // same op order as ref
        }
    }
}

// ---------------- K3: 64x64 tiles, write-all (no memset) ---------------
__global__ __launch_bounds__(64) void k3_mask(
    const int* __restrict__ n_arr,
    const float* __restrict__ ox1, const float* __restrict__ oy1,
    const float* __restrict__ ox2, const float* __restrict__ oy2,
    const float* __restrict__ area, uint64_t* __restrict__ mask64) {
    __shared__ float jx1[CH], jy1[CH], jx2[CH], jy2[CH], jar[CH];
    int img = blockIdx.y;
    int n = n_arr[img];
    int ci = blockIdx.x >> 5, cj = blockIdx.x & 31;
    int t = threadIdx.x;
    size_t base = (size_t)img * NCAND;
    int i = ci * CH + t;
    uint64_t w = 0;
    if (cj >= ci && ci * CH < n && cj * CH < n) {   // block-uniform
        {
            int j = cj * CH + t;
            float x1 = 0.f, y1 = 0.f, x2 = 0.f, y2 = 0.f, ar = 0.f;
            if (j < n) {
                x1 = ox1[base + j]; y1 = oy1[base + j];
                x2 = ox2[base + j]; y2 = oy2[base + j]; ar = area[base + j];
            }
            jx1[t] = x1; jy1[t] = y1; jx2[t] = x2; jy2[t] = y2; jar[t] = ar;
        }
        __syncthreads();
        float ax1 = 0.f, ay1 = 0.f, ax2 = 0.f, ay2 = 0.f, aar = 0.f;
        if (i < n) {
            ax1 = ox1[base + i]; ay1 = oy1[base + i];
            ax2 = ox2[base + i]; ay2 = oy2[base + i]; aar = area[base + i];
        }
        int jg0 = cj * CH;
#pragma unroll 8
        for (int jj = 0; jj < CH; ++jj) {
            float ltx = fmaxf(ax1, jx1[jj]), lty = fmaxf(ay1, jy1[jj]);
            float rbx = fminf(ax2, jx2[jj]), rby = fminf(ay2, jy2[jj]);
            float ww = fmaxf(rbx - ltx, 0.f), hh = fmaxf(rby - lty, 0.f);
            float inter = ww * hh;
            float iou = inter / (aar + jar[jj] - inter + 1e-9f);  // IEEE div
            w |= (iou > IOUT && (jg0 + jj) > i) ? (1ull << jj) : 0ull;
        }
    }
    mask64[(base + (size_t)i) * NCH + cj] = w;
}

// ---------------- K4: serial greedy scan + top-300 output --------------
__global__ void k4_scan(const int* __restrict__ n_arr,
                        const uint32_t* __restrict__ mask,
                        const float* __restrict__ score, const int* __restrict__ label,
                        const float* __restrict__ rx1, const float* __restrict__ ry1,
                        const float* __restrict__ rx2, const float* __restrict__ ry2,
                        float* __restrict__ out) {
    int img = blockIdx.x;
    int lane = threadIdx.x;   // 64 threads = 1 wave
    int n = n_arr[img];
    size_t cbase = (size_t)img * NCAND;
    const uint32_t* rowp = mask + cbase * 64 + lane;
    float* outp = out + (size_t)img * NDET * 6;

    uint32_t removed = 0;
    int kcnt = 0;
    constexpr int PF = 32;
    uint32_t buf[PF];
#pragma unroll
    for (int k = 0; k < PF; ++k) buf[k] = rowp[(size_t)k * 64];
    for (int ib = 0; ib < n; ib += PF) {
#pragma unroll
        for (int k = 0; k < PF; ++k) {
            int i = ib + k;
            uint32_t row = buf[k];
            int pi = i + PF; if (pi > NCAND - 1) pi = NCAND - 1;
            buf[k] = rowp[(size_t)pi * 64];
            // blocked layout: word at lane i>>5, bit i&31. i uniform.
            uint32_t w = (uint32_t)__builtin_amdgcn_readlane((int)removed, i >> 5);
            uint32_t kept = ((w >> (i & 31)) & 1u) ^ 1u;
            kcnt += (int)kept;                      // phantom i>=n harmless
            removed |= row & (0u - kept);
        }
        if (kcnt >= NDET) break;                    // uniform early stop
    }

    int j0 = lane << 5;
    uint32_t vmask = (j0 + 32 <= n) ? 0xffffffffu
                   : (j0 >= n ? 0u : ((1u << (n - j0)) - 1u));
    uint32_t keptw = ~removed & vmask;
    int cntk = __popc(keptw);
    int pre = cntk;
    for (int d = 1; d < 64; d <<= 1) {              // inclusive prefix
        int tv = __shfl_up(pre, d);
        if (lane >= d) pre += tv;
    }
    int totalk = __shfl(pre, 63);
    int r = pre - cntk;                             // exclusive prefix
    uint32_t wvb = keptw;
    while (wvb) {
        int b = __builtin_ctz(wvb);
        wvb &= wvb - 1;
        if (r >= NDET) break;
        int j = j0 + b;
        float* o = outp + (size_t)r * 6;
        o[0] = rx1[cbase + j]; o[1] = ry1[cbase + j];
        o[2] = rx2[cbase + j]; o[3] = ry2[cbase + j];
        o[4] = score[cbase + j]; o[5] = (float)label[cbase + j];
        ++r;
    }
    int nk = totalk < NDET ? totalk : NDET;
    for (int idx = nk * 6 + lane; idx < NDET * 6; idx += 64) outp[idx] = 0.0f;
}

// ---------------- launch: 4 dispatches -------------------------------
extern "C" void kernel_launch(void* const* d_in, const int* in_sizes, int n_in,
                              void* d_out, int out_size, void* d_ws, size_t ws_size,
                              hipStream_t stream) {
    const float* pred = (const float*)d_in[0];
    float* out = (float*)d_out;
    char* w = (char*)d_ws;

    const size_t A_BC  = 0;                                 // 8*256 ints
    const size_t A_RK  = 8192;                              // 8*225*96*8 keys
    const size_t SA    = A_RK + (size_t)NIMG * NSEG * SEGCAP * 8;
    const size_t A_N   = SA;                                // 8 ints (pad 256)
    const size_t SB    = SA + 256;
    const size_t SZ_S  = (size_t)NIMG * NCAND * 4;          // 64 KiB each

    int*      bcnt  = (int*)(w + A_BC);
    uint64_t* raw_k = (uint64_t*)(w + A_RK);
    int*      n_arr = (int*)(w + A_N);
    float* score = (float*)(w + SB + 0 * SZ_S);
    int*   label = (int*)(w + SB + 1 * SZ_S);
    float* ox1   = (float*)(w + SB + 2 * SZ_S);
    float* oy1   = (float*)(w + SB + 3 * SZ_S);
    float* ox2   = (float*)(w + SB + 4 * SZ_S);
    float* oy2   = (float*)(w + SB + 5 * SZ_S);
    float* area  = (float*)(w + SB + 6 * SZ_S);
    float* rx1   = (float*)(w + SB + 7 * SZ_S);
    float* ry1   = (float*)(w + SB + 8 * SZ_S);
    float* rx2   = (float*)(w + SB + 9 * SZ_S);
    float* ry2   = (float*)(w + SB + 10 * SZ_S);
    uint64_t* mask64 = (uint64_t*)(w + SB + 11 * SZ_S);     // 4 MiB
    uint32_t* mask32 = (uint32_t*)mask64;

    dim3 g1(NSEG, NIMG);                                    // 225 x 8
    k1_filter<<<g1, 128, 0, stream>>>(pred, bcnt, raw_k);
    dim3 g2(CAPRAW / K2U, NIMG);                            // 64 x 8
    k2_rank<<<g2, 256, 0, stream>>>(pred, bcnt, raw_k, n_arr,
        score, label, ox1, oy1, ox2, oy2, area, rx1, ry1, rx2, ry2);
    dim3 g3(NCH * NCH, NIMG);                               // 1024 x 8
    k3_mask<<<g3, CH, 0, stream>>>(n_arr, ox1, oy1, ox2, oy2, area, mask64);
    k4_scan<<<NIMG, 64, 0, stream>>>(n_arr, mask32, score, label,
        rx1, ry1, rx2, ry2, out);
}